// Round 1
// baseline (288.603 us; speedup 1.0000x reference)
//
#include <hip/hip_runtime.h>
#include <hip/hip_bf16.h>
#include <math.h>

#define D_MODEL 256
#define EXPERT_DIM 512
#define NUM_EXPERTS 8
#define T_TOKENS 4096
#define TM 32

// ---------------------------------------------------------------------------
// Kernel 1: gating. One thread per token: 8 gate logits, top-2, softmax,
// atomic append into per-expert token lists in workspace.
// ---------------------------------------------------------------------------
__global__ __launch_bounds__(256) void moe_gate_kernel(
    const float* __restrict__ x, const float* __restrict__ Wg,
    const float* __restrict__ bg, const float* __restrict__ bias,
    int* __restrict__ counts, int* __restrict__ lists, float* __restrict__ wts)
{
    int t = blockIdx.x * blockDim.x + threadIdx.x;
    if (t >= T_TOKENS) return;
    const float4* x4 = reinterpret_cast<const float4*>(x + t * D_MODEL);
    float acc[NUM_EXPERTS];
#pragma unroll
    for (int e = 0; e < NUM_EXPERTS; ++e) acc[e] = 0.f;
    for (int i4 = 0; i4 < D_MODEL / 4; ++i4) {
        float4 xv = x4[i4];
        const float* wrow = Wg + i4 * 4 * NUM_EXPERTS;   // Wg[i][e] = Wg[i*8+e]
#pragma unroll
        for (int e = 0; e < NUM_EXPERTS; ++e) {
            acc[e] += xv.x * wrow[e]
                    + xv.y * wrow[NUM_EXPERTS + e]
                    + xv.z * wrow[2 * NUM_EXPERTS + e]
                    + xv.w * wrow[3 * NUM_EXPERTS + e];
        }
    }
    // top-2, strict > keeps lowest index on ties (matches jax.lax.top_k)
    float v0 = -3.0e38f, v1 = -3.0e38f; int i0 = 0, i1 = 0;
#pragma unroll
    for (int e = 0; e < NUM_EXPERTS; ++e) {
        float v = acc[e] + bg[e] + bias[e];
        if (v > v0) { v1 = v0; i1 = i0; v0 = v; i0 = e; }
        else if (v > v1) { v1 = v; i1 = e; }
    }
    // softmax over [v0, v1], v0 >= v1
    float e1 = __expf(v1 - v0);
    float inv = 1.f / (1.f + e1);
    float w0 = inv, w1 = e1 * inv;

    int p0 = atomicAdd(&counts[i0], 1);
    lists[i0 * T_TOKENS + p0] = t;
    wts  [i0 * T_TOKENS + p0] = w0;
    int p1 = atomicAdd(&counts[i1], 1);
    lists[i1 * T_TOKENS + p1] = t;
    wts  [i1 * T_TOKENS + p1] = w1;
}

// ---------------------------------------------------------------------------
// Kernel 2: expert FFN over routed token tiles.
// grid = (expert, tile). block = 512 threads. TM=32 tokens per tile.
// LDS: xs 32x256 (32KB) + hs 32x256 (32KB, one half of h at a time) = 64KB.
// Thread (dq = tid&127, rq = tid>>7) owns 8 rows x 2 cols -> 16 accumulators;
// inner loops read A/h via wave-uniform ds_read_b128 broadcasts:
// 8 b128 reads per 64 FMAs -> FMA-bound.
// ---------------------------------------------------------------------------
__global__ __launch_bounds__(512) void moe_expert_kernel(
    const float* __restrict__ x,
    const float* __restrict__ W1, const float* __restrict__ b1,
    const float* __restrict__ W2, const float* __restrict__ b2,
    const int* __restrict__ counts, const int* __restrict__ lists,
    const float* __restrict__ wts, float* __restrict__ out)
{
    const int e = blockIdx.x;
    const int n = counts[e];
    const int base = blockIdx.y * TM;
    if (base >= n) return;
    const int m = min(TM, n - base);

    __shared__ float xs[TM][D_MODEL];   // 32 KB
    __shared__ float hs[TM][D_MODEL];   // 32 KB (one 256-wide half of h)

    const int tid = threadIdx.x;
    const int* lst = lists + e * T_TOKENS + base;

    // gather x rows for this tile (zeros for padding rows)
    for (int idx = tid; idx < TM * D_MODEL / 4; idx += 512) {
        int r = idx >> 6, c4 = idx & 63;
        float4 v = make_float4(0.f, 0.f, 0.f, 0.f);
        if (r < m) {
            int tok = lst[r];
            v = reinterpret_cast<const float4*>(x + tok * D_MODEL)[c4];
        }
        reinterpret_cast<float4*>(&xs[r][0])[c4] = v;
    }
    __syncthreads();

    const int dq = tid & 127;        // column lane: handles col dq and dq+128
    const int r0 = (tid >> 7) * 8;   // row block: 8 rows

    const float* W1e = W1 + e * D_MODEL * EXPERT_DIM;
    const float* W2e = W2 + e * EXPERT_DIM * D_MODEL;

    float acc2[16];
#pragma unroll
    for (int k = 0; k < 16; ++k) acc2[k] = 0.f;

    for (int hh = 0; hh < 2; ++hh) {
        const int j0 = hh * 256 + dq;          // h-column in [0,512)
        float a[16];
#pragma unroll
        for (int k = 0; k < 16; ++k) a[k] = 0.f;

        // stage 1: h[r][j0], h[r][j0+128] = x-tile @ W1 columns
        for (int i4 = 0; i4 < D_MODEL / 4; ++i4) {
            const int i = i4 * 4;
            const float* wp = W1e + i * EXPERT_DIM + j0;
            float wA0 = wp[0],              wB0 = wp[128];
            float wA1 = wp[EXPERT_DIM],     wB1 = wp[EXPERT_DIM + 128];
            float wA2 = wp[2 * EXPERT_DIM], wB2 = wp[2 * EXPERT_DIM + 128];
            float wA3 = wp[3 * EXPERT_DIM], wB3 = wp[3 * EXPERT_DIM + 128];
#pragma unroll
            for (int rr = 0; rr < 8; ++rr) {
                float4 xv = *reinterpret_cast<const float4*>(&xs[r0 + rr][i]);
                a[rr]     += xv.x * wA0 + xv.y * wA1 + xv.z * wA2 + xv.w * wA3;
                a[8 + rr] += xv.x * wB0 + xv.y * wB1 + xv.z * wB2 + xv.w * wB3;
            }
        }
        float bA = b1[e * EXPERT_DIM + j0];
        float bB = b1[e * EXPERT_DIM + j0 + 128];
        __syncthreads();   // prior stage-2 reads of hs are done
#pragma unroll
        for (int rr = 0; rr < 8; ++rr) {
            hs[r0 + rr][dq]       = fmaxf(a[rr]     + bA, 0.f);
            hs[r0 + rr][dq + 128] = fmaxf(a[8 + rr] + bB, 0.f);
        }
        __syncthreads();

        // stage 2: partial y += h-half @ W2[hh*256 : hh*256+256, :]
        const float* W2h = W2e + (hh * 256) * D_MODEL;
        for (int j4 = 0; j4 < 64; ++j4) {
            const int j = j4 * 4;
            const float* wp = W2h + j * D_MODEL + dq;
            float wA0 = wp[0],            wB0 = wp[128];
            float wA1 = wp[D_MODEL],      wB1 = wp[D_MODEL + 128];
            float wA2 = wp[2 * D_MODEL],  wB2 = wp[2 * D_MODEL + 128];
            float wA3 = wp[3 * D_MODEL],  wB3 = wp[3 * D_MODEL + 128];
#pragma unroll
            for (int rr = 0; rr < 8; ++rr) {
                float4 hv = *reinterpret_cast<const float4*>(&hs[r0 + rr][j]);
                acc2[rr]     += hv.x * wA0 + hv.y * wA1 + hv.z * wA2 + hv.w * wA3;
                acc2[8 + rr] += hv.x * wB0 + hv.y * wB1 + hv.z * wB2 + hv.w * wB3;
            }
        }
    }

    // epilogue: out[tok] += w * (y + b2); two expert blocks touch each token
    const float bA = b2[e * D_MODEL + dq];
    const float bB = b2[e * D_MODEL + dq + 128];
    const float* wrow = wts + e * T_TOKENS + base;
#pragma unroll
    for (int rr = 0; rr < 8; ++rr) {
        int r = r0 + rr;
        if (r < m) {
            int tok = lst[r];
            float w = wrow[r];
            atomicAdd(&out[tok * D_MODEL + dq],       w * (acc2[rr]     + bA));
            atomicAdd(&out[tok * D_MODEL + dq + 128], w * (acc2[8 + rr] + bB));
        }
    }
}

extern "C" void kernel_launch(void* const* d_in, const int* in_sizes, int n_in,
                              void* d_out, int out_size, void* d_ws, size_t ws_size,
                              hipStream_t stream)
{
    const float* x    = (const float*)d_in[0];
    const float* Wg   = (const float*)d_in[1];
    const float* bg   = (const float*)d_in[2];
    const float* bias = (const float*)d_in[3];
    const float* W1   = (const float*)d_in[4];
    const float* b1   = (const float*)d_in[5];
    const float* W2   = (const float*)d_in[6];
    const float* b2   = (const float*)d_in[7];
    float* out = (float*)d_out;

    // workspace layout: counts (8 ints, padded to 256B) | lists | wts
    char* ws = (char*)d_ws;
    int*   counts = (int*)ws;
    int*   lists  = (int*)(ws + 256);
    float* wts    = (float*)(ws + 256 + NUM_EXPERTS * T_TOKENS * sizeof(int));

    hipMemsetAsync(out, 0, (size_t)out_size * sizeof(float), stream);
    hipMemsetAsync(counts, 0, NUM_EXPERTS * sizeof(int), stream);

    moe_gate_kernel<<<T_TOKENS / 256, 256, 0, stream>>>(
        x, Wg, bg, bias, counts, lists, wts);

    moe_expert_kernel<<<dim3(NUM_EXPERTS, T_TOKENS / TM), 512, 0, stream>>>(
        x, W1, b1, W2, b2, counts, lists, wts, out);
}

// Round 2
// 216.961 us; speedup vs baseline: 1.3302x; 1.3302x over previous
//
#include <hip/hip_runtime.h>
#include <hip/hip_bf16.h>
#include <math.h>

#define D_MODEL 256
#define EXPERT_DIM 512
#define NUM_EXPERTS 8
#define T_TOKENS 4096
#define TM 32
#define XS_LD 264   // 256 + 8 bf16 pad: row stride 528B -> 2-way bank alias (free)
#define HS_LD 520   // 512 + 8 bf16 pad: row stride 1040B -> 2-way bank alias (free)

typedef unsigned short ushort_t;
typedef short short8_t __attribute__((ext_vector_type(8)));
typedef float f32x4 __attribute__((ext_vector_type(4)));

__device__ __forceinline__ ushort_t f2bf(float f) {
    unsigned int u = __float_as_uint(f);
    u += 0x7FFFu + ((u >> 16) & 1u);   // round-to-nearest-even
    return (ushort_t)(u >> 16);
}

// ---------------------------------------------------------------------------
// Transpose + fp32->bf16 convert: src [E][K][N] fp32 -> dst [E][N][K] bf16.
// grid (E, K/32, N/32), block 256. 32x32 tile via LDS (pad 33 -> conflict-free).
// ---------------------------------------------------------------------------
__global__ __launch_bounds__(256) void convert_transpose_kernel(
    const float* __restrict__ src, ushort_t* __restrict__ dst, int K, int N)
{
    __shared__ float tile[32][33];
    const int e = blockIdx.x, kt = blockIdx.y, nt = blockIdx.z;
    const int tid = threadIdx.x;

    const float* srcp = src + ((size_t)e * K + kt * 32) * N + nt * 32;
    ushort_t* dstp = dst + ((size_t)e * N + nt * 32) * K + kt * 32;

    int r = tid >> 3, c4 = tid & 7;
    float4 v = *(const float4*)&srcp[r * N + c4 * 4];
    tile[r][c4 * 4 + 0] = v.x; tile[r][c4 * 4 + 1] = v.y;
    tile[r][c4 * 4 + 2] = v.z; tile[r][c4 * 4 + 3] = v.w;
    __syncthreads();

    int nn = tid >> 3, k4 = tid & 7;
    ushort4 o;
    o.x = f2bf(tile[k4 * 4 + 0][nn]);
    o.y = f2bf(tile[k4 * 4 + 1][nn]);
    o.z = f2bf(tile[k4 * 4 + 2][nn]);
    o.w = f2bf(tile[k4 * 4 + 3][nn]);
    *(ushort4*)&dstp[nn * K + k4 * 4] = o;
}

// ---------------------------------------------------------------------------
// Gate: one wave per token. Coalesced x row read (64 lanes x float4 = 1KB),
// fused bf16 conversion of x, butterfly-reduced gate logits, top-2 + softmax,
// atomic append into per-expert lists.
// ---------------------------------------------------------------------------
__global__ __launch_bounds__(256) void moe_gate_kernel(
    const float* __restrict__ x, const float* __restrict__ Wg,
    const float* __restrict__ bg, const float* __restrict__ bias,
    ushort_t* __restrict__ xb,
    int* __restrict__ counts, int* __restrict__ lists, float* __restrict__ wts)
{
    const int t = blockIdx.x * 4 + (threadIdx.x >> 6);
    const int lane = threadIdx.x & 63;

    float4 xv = reinterpret_cast<const float4*>(x + t * D_MODEL)[lane];

    // fused bf16 conversion of x (coalesced 8B stores)
    ushort4 xo;
    xo.x = f2bf(xv.x); xo.y = f2bf(xv.y); xo.z = f2bf(xv.z); xo.w = f2bf(xv.w);
    *(ushort4*)&xb[t * D_MODEL + lane * 4] = xo;

    // Wg rows lane*4 .. lane*4+3 -> 128B contiguous per lane, coalesced
    float wv[32];
    const float4* wg4 = (const float4*)(Wg + lane * 4 * NUM_EXPERTS);
#pragma unroll
    for (int q = 0; q < 8; ++q) {
        float4 w = wg4[q];
        wv[q * 4 + 0] = w.x; wv[q * 4 + 1] = w.y; wv[q * 4 + 2] = w.z; wv[q * 4 + 3] = w.w;
    }
    float acc[NUM_EXPERTS];
#pragma unroll
    for (int e = 0; e < NUM_EXPERTS; ++e)
        acc[e] = xv.x * wv[e] + xv.y * wv[8 + e] + xv.z * wv[16 + e] + xv.w * wv[24 + e];
    // wave butterfly reduce
#pragma unroll
    for (int e = 0; e < NUM_EXPERTS; ++e) {
#pragma unroll
        for (int s = 1; s < 64; s <<= 1) acc[e] += __shfl_xor(acc[e], s);
    }
    if (lane == 0) {
        float v0 = -3.0e38f, v1 = -3.0e38f; int i0 = 0, i1 = 0;
#pragma unroll
        for (int e = 0; e < NUM_EXPERTS; ++e) {
            float v = acc[e] + bg[e] + bias[e];
            if (v > v0) { v1 = v0; i1 = i0; v0 = v; i0 = e; }
            else if (v > v1) { v1 = v; i1 = e; }
        }
        float e1 = __expf(v1 - v0);
        float inv = 1.f / (1.f + e1);
        int p0 = atomicAdd(&counts[i0], 1);
        lists[i0 * T_TOKENS + p0] = t;
        wts  [i0 * T_TOKENS + p0] = inv;
        int p1 = atomicAdd(&counts[i1], 1);
        lists[i1 * T_TOKENS + p1] = t;
        wts  [i1 * T_TOKENS + p1] = e1 * inv;
    }
}

// ---------------------------------------------------------------------------
// Expert FFN, bf16 MFMA. grid (expert, tile), block 256 = 4 waves, TM=32.
// Wave w owns n-quarter. Stage1: H[32][512]=relu(X@W1+b1); stage2:
// Y[32][256]=H@W2; epilogue: out[tok] += w*(Y+b2) via fp32 atomics.
// A-frag: A[m=lane&15][k=quad*8+j] (ds_read_b128 from LDS).
// B-frag: B[k=quad*8+j][n=lane&15] from pre-transposed bf16 weights [n][k].
// C/D:    D[row=quad*4+reg][col=lane&15].
// B-frags double-buffered across the K loop to hide L2 latency.
// ---------------------------------------------------------------------------
__global__ __launch_bounds__(256) void moe_expert_mfma(
    const ushort_t* __restrict__ xb,
    const ushort_t* __restrict__ W1t, const float* __restrict__ b1,
    const ushort_t* __restrict__ W2t, const float* __restrict__ b2,
    const int* __restrict__ counts, const int* __restrict__ lists,
    const float* __restrict__ wts, float* __restrict__ out)
{
    const int e = blockIdx.x;
    const int n = counts[e];
    const int base = blockIdx.y * TM;
    if (base >= n) return;
    const int m = min(TM, n - base);

    __shared__ ushort_t Xs[TM * XS_LD];
    __shared__ ushort_t Hs[TM * HS_LD];
    __shared__ int   toks[TM];
    __shared__ float wt_s[TM];

    const int tid = threadIdx.x;
    if (tid < TM) {
        const int* lst = lists + e * T_TOKENS + base;
        const float* wr = wts + e * T_TOKENS + base;
        toks[tid] = (tid < m) ? lst[tid] : -1;
        wt_s[tid] = (tid < m) ? wr[tid] : 0.f;
    }
    __syncthreads();

    // gather X tile (bf16), zeros for padding rows
    for (int c = tid; c < TM * 32; c += 256) {
        int r = c >> 5, c8 = c & 31;
        int tk = toks[r];
        int4 v = make_int4(0, 0, 0, 0);
        if (tk >= 0) v = *(const int4*)(xb + tk * D_MODEL + c8 * 8);
        *(int4*)(Xs + r * XS_LD + c8 * 8) = v;
    }
    __syncthreads();

    const int lane = tid & 63;
    const int w = tid >> 6;        // wave id: n-quarter
    const int l15 = lane & 15;
    const int quad = lane >> 4;

    // ---------------- stage 1: H = relu(X @ W1 + b1) ----------------
    const ushort_t* W1w = W1t + (size_t)e * EXPERT_DIM * D_MODEL
                         + (w * 128 + l15) * D_MODEL + quad * 8;
    float b1v[8];
#pragma unroll
    for (int nt = 0; nt < 8; ++nt) b1v[nt] = b1[e * EXPERT_DIM + w * 128 + nt * 16 + l15];

    f32x4 acc1[2][8] = {};
    short8_t bc[8];
#pragma unroll
    for (int nt = 0; nt < 8; ++nt) bc[nt] = *(const short8_t*)(W1w + nt * 16 * D_MODEL);

    for (int ks = 0; ks < 8; ++ks) {
        short8_t bn[8];
        if (ks < 7) {
#pragma unroll
            for (int nt = 0; nt < 8; ++nt)
                bn[nt] = *(const short8_t*)(W1w + (ks + 1) * 32 + nt * 16 * D_MODEL);
        }
        short8_t a0 = *(const short8_t*)(Xs + l15 * XS_LD + ks * 32 + quad * 8);
        short8_t a1 = *(const short8_t*)(Xs + (16 + l15) * XS_LD + ks * 32 + quad * 8);
#pragma unroll
        for (int nt = 0; nt < 8; ++nt) {
            acc1[0][nt] = __builtin_amdgcn_mfma_f32_16x16x32_bf16(a0, bc[nt], acc1[0][nt], 0, 0, 0);
            acc1[1][nt] = __builtin_amdgcn_mfma_f32_16x16x32_bf16(a1, bc[nt], acc1[1][nt], 0, 0, 0);
        }
        if (ks < 7) {
#pragma unroll
            for (int nt = 0; nt < 8; ++nt) bc[nt] = bn[nt];
        }
    }
    // relu + bias -> Hs (bf16)
#pragma unroll
    for (int mt = 0; mt < 2; ++mt)
#pragma unroll
        for (int nt = 0; nt < 8; ++nt)
#pragma unroll
            for (int r = 0; r < 4; ++r) {
                int row = mt * 16 + quad * 4 + r;
                int col = w * 128 + nt * 16 + l15;
                float h = fmaxf(acc1[mt][nt][r] + b1v[nt], 0.f);
                Hs[row * HS_LD + col] = f2bf(h);
            }
    __syncthreads();

    // ---------------- stage 2: Y = H @ W2 ----------------
    const ushort_t* W2w = W2t + (size_t)e * D_MODEL * EXPERT_DIM
                         + (w * 64 + l15) * EXPERT_DIM + quad * 8;
    float b2v[4];
#pragma unroll
    for (int nt = 0; nt < 4; ++nt) b2v[nt] = b2[e * D_MODEL + w * 64 + nt * 16 + l15];

    f32x4 acc2[2][4] = {};
    short8_t bc2[4];
#pragma unroll
    for (int nt = 0; nt < 4; ++nt) bc2[nt] = *(const short8_t*)(W2w + nt * 16 * EXPERT_DIM);

    for (int ks = 0; ks < 16; ++ks) {
        short8_t bn2[4];
        if (ks < 15) {
#pragma unroll
            for (int nt = 0; nt < 4; ++nt)
                bn2[nt] = *(const short8_t*)(W2w + (ks + 1) * 32 + nt * 16 * EXPERT_DIM);
        }
        short8_t a0 = *(const short8_t*)(Hs + l15 * HS_LD + ks * 32 + quad * 8);
        short8_t a1 = *(const short8_t*)(Hs + (16 + l15) * HS_LD + ks * 32 + quad * 8);
#pragma unroll
        for (int nt = 0; nt < 4; ++nt) {
            acc2[0][nt] = __builtin_amdgcn_mfma_f32_16x16x32_bf16(a0, bc2[nt], acc2[0][nt], 0, 0, 0);
            acc2[1][nt] = __builtin_amdgcn_mfma_f32_16x16x32_bf16(a1, bc2[nt], acc2[1][nt], 0, 0, 0);
        }
        if (ks < 15) {
#pragma unroll
            for (int nt = 0; nt < 4; ++nt) bc2[nt] = bn2[nt];
        }
    }

    // epilogue: out[tok] += w * (y + b2)
#pragma unroll
    for (int mt = 0; mt < 2; ++mt)
#pragma unroll
        for (int nt = 0; nt < 4; ++nt)
#pragma unroll
            for (int r = 0; r < 4; ++r) {
                int row = mt * 16 + quad * 4 + r;
                int tk = toks[row];
                if (tk >= 0) {
                    int col = w * 64 + nt * 16 + l15;
                    atomicAdd(&out[tk * D_MODEL + col],
                              wt_s[row] * (acc2[mt][nt][r] + b2v[nt]));
                }
            }
}

extern "C" void kernel_launch(void* const* d_in, const int* in_sizes, int n_in,
                              void* d_out, int out_size, void* d_ws, size_t ws_size,
                              hipStream_t stream)
{
    const float* x    = (const float*)d_in[0];
    const float* Wg   = (const float*)d_in[1];
    const float* bg   = (const float*)d_in[2];
    const float* bias = (const float*)d_in[3];
    const float* W1   = (const float*)d_in[4];
    const float* b1   = (const float*)d_in[5];
    const float* W2   = (const float*)d_in[6];
    const float* b2   = (const float*)d_in[7];
    float* out = (float*)d_out;

    // workspace layout
    char* ws = (char*)d_ws;
    int*      counts = (int*)ws;                                   // 256 B
    int*      lists  = (int*)(ws + 256);                           // 128 KB
    float*    wts    = (float*)(ws + 256 + 131072);                // 128 KB
    ushort_t* xb     = (ushort_t*)(ws + 256 + 262144);             // 2 MB
    ushort_t* W1t    = (ushort_t*)(ws + 256 + 262144 + 2097152);   // 2 MB
    ushort_t* W2t    = (ushort_t*)(ws + 256 + 262144 + 4194304);   // 2 MB

    hipMemsetAsync(out, 0, (size_t)out_size * sizeof(float), stream);
    hipMemsetAsync(counts, 0, NUM_EXPERTS * sizeof(int), stream);

    convert_transpose_kernel<<<dim3(NUM_EXPERTS, D_MODEL / 32, EXPERT_DIM / 32), 256, 0, stream>>>(
        W1, W1t, D_MODEL, EXPERT_DIM);
    convert_transpose_kernel<<<dim3(NUM_EXPERTS, EXPERT_DIM / 32, D_MODEL / 32), 256, 0, stream>>>(
        W2, W2t, EXPERT_DIM, D_MODEL);

    moe_gate_kernel<<<T_TOKENS / 4, 256, 0, stream>>>(
        x, Wg, bg, bias, xb, counts, lists, wts);

    moe_expert_mfma<<<dim3(NUM_EXPERTS, T_TOKENS / TM), 256, 0, stream>>>(
        xb, W1t, b1, W2t, b2, counts, lists, wts, out);
}

// Round 3
// 120.436 us; speedup vs baseline: 2.3963x; 1.8015x over previous
//
#include <hip/hip_runtime.h>
#include <hip/hip_bf16.h>
#include <math.h>

#define D_MODEL 256
#define EXPERT_DIM 512
#define NUM_EXPERTS 8
#define T_TOKENS 4096
#define TM 32
#define XS_LD 264   // 256 + 8 bf16 pad (528 B row): balanced b128 banking

typedef unsigned short ushort_t;
typedef short short8_t __attribute__((ext_vector_type(8)));
typedef float f32x4 __attribute__((ext_vector_type(4)));

__device__ __forceinline__ ushort_t f2bf(float f) {
    unsigned int u = __float_as_uint(f);
    u += 0x7FFFu + ((u >> 16) & 1u);   // round-to-nearest-even
    return (ushort_t)(u >> 16);
}

// ---------------------------------------------------------------------------
// Weight conversion: fp32 [E][K][N] -> bf16 MFMA-fragment order.
// W1f idx bits: e<<14 | ntile<<9 | ks<<6 | lane   (x8 bf16 elems, j=k&7)
// W2f idx bits: e<<14 | half<<13 | ntile<<9 | ks<<6 | lane
// element (k,n): lane = (k>>3 & 3)*16 + (n&15); ks = k>>5 (local); j = k&7.
// One thread per 8-elem fragment chunk (reads 8 floats stride N).
// ---------------------------------------------------------------------------
__global__ __launch_bounds__(256) void convert_frag_kernel(
    const float* __restrict__ W1, const float* __restrict__ W2,
    ushort_t* __restrict__ W1f, ushort_t* __restrict__ W2f)
{
    int gid = blockIdx.x * 256 + threadIdx.x;      // 0 .. 262143
    bool isW2 = gid >= 131072;
    int idx = isW2 ? gid - 131072 : gid;
    int lane = idx & 63;
    int l15 = lane & 15, quad = lane >> 4;
    int ks = (idx >> 6) & 7;
    ushort_t o[8];
    if (!isW2) {
        int ntile = (idx >> 9) & 31, e = idx >> 14;
        int nn = ntile * 16 + l15;
        int k0 = ks * 32 + quad * 8;
        const float* s = W1 + ((size_t)e * D_MODEL + k0) * EXPERT_DIM + nn;
#pragma unroll
        for (int j = 0; j < 8; ++j) o[j] = f2bf(s[j * EXPERT_DIM]);
        *(int4*)(W1f + (size_t)idx * 8) = *(int4*)o;
    } else {
        int ntile = (idx >> 9) & 15, half = (idx >> 13) & 1, e = idx >> 14;
        int nn = ntile * 16 + l15;
        int k0 = half * 256 + ks * 32 + quad * 8;
        const float* s = W2 + ((size_t)e * EXPERT_DIM + k0) * D_MODEL + nn;
#pragma unroll
        for (int j = 0; j < 8; ++j) o[j] = f2bf(s[j * D_MODEL]);
        *(int4*)(W2f + (size_t)idx * 8) = *(int4*)o;
    }
}

// ---------------------------------------------------------------------------
// Gate: one thread per token, 16 blocks. Per-block LDS expert histogram ->
// ONE global atomicAdd per (expert, block) = 128 total (was 16384 same-line
// device atomics = 97 us of serialization).
// ---------------------------------------------------------------------------
__global__ __launch_bounds__(256) void moe_gate_kernel(
    const float* __restrict__ x, const float* __restrict__ Wg,
    const float* __restrict__ bg, const float* __restrict__ bias,
    int* __restrict__ counts, int* __restrict__ lists, float* __restrict__ wts)
{
    __shared__ int lcount[NUM_EXPERTS];
    __shared__ int lbase[NUM_EXPERTS];
    const int tid = threadIdx.x;
    const int t = blockIdx.x * 256 + tid;
    if (tid < NUM_EXPERTS) lcount[tid] = 0;

    const float4* x4 = reinterpret_cast<const float4*>(x + t * D_MODEL);
    float acc[NUM_EXPERTS];
#pragma unroll
    for (int e = 0; e < NUM_EXPERTS; ++e) acc[e] = 0.f;
    for (int i4 = 0; i4 < D_MODEL / 4; ++i4) {
        float4 xv = x4[i4];
        const float* wrow = Wg + i4 * 4 * NUM_EXPERTS;
#pragma unroll
        for (int e = 0; e < NUM_EXPERTS; ++e) {
            acc[e] += xv.x * wrow[e]
                    + xv.y * wrow[NUM_EXPERTS + e]
                    + xv.z * wrow[2 * NUM_EXPERTS + e]
                    + xv.w * wrow[3 * NUM_EXPERTS + e];
        }
    }
    float v0 = -3.0e38f, v1 = -3.0e38f; int i0 = 0, i1 = 0;
#pragma unroll
    for (int e = 0; e < NUM_EXPERTS; ++e) {
        float v = acc[e] + bg[e] + bias[e];
        if (v > v0) { v1 = v0; i1 = i0; v0 = v; i0 = e; }
        else if (v > v1) { v1 = v; i1 = e; }
    }
    float e1 = __expf(v1 - v0);
    float inv = 1.f / (1.f + e1);
    float w0 = inv, w1 = e1 * inv;

    __syncthreads();
    int p0 = atomicAdd(&lcount[i0], 1);       // LDS atomics (per-CU, fast)
    int p1 = atomicAdd(&lcount[i1], 1);
    __syncthreads();
    if (tid < NUM_EXPERTS) lbase[tid] = atomicAdd(&counts[tid], lcount[tid]);
    __syncthreads();
    int q0 = lbase[i0] + p0;
    int q1 = lbase[i1] + p1;
    lists[i0 * T_TOKENS + q0] = t;  wts[i0 * T_TOKENS + q0] = w0;
    lists[i1 * T_TOKENS + q1] = t;  wts[i1 * T_TOKENS + q1] = w1;
}

// ---------------------------------------------------------------------------
// Expert FFN, bf16 MFMA. grid (expert, half, tile), block 256 = 4 waves.
// Each block handles a 256-wide half of EXPERT_DIM: stage1 H_half =
// relu(X @ W1[:,half]+b1), stage2 partial Y = H_half @ W2[half rows,:],
// epilogue out[tok] += w*(Y + (half? b2:0)) via fp32 atomics.
// B-frags: one contiguous 1KB wave-load from fragment-ordered weights,
// double-buffered across the K loop. LDS 34 KB -> 4 blocks/CU.
// ---------------------------------------------------------------------------
__global__ __launch_bounds__(256) void moe_expert_mfma(
    const float* __restrict__ x,
    const ushort_t* __restrict__ W1f, const float* __restrict__ b1,
    const ushort_t* __restrict__ W2f, const float* __restrict__ b2,
    const int* __restrict__ counts, const int* __restrict__ lists,
    const float* __restrict__ wts, float* __restrict__ out)
{
    const int e = blockIdx.x;
    const int half = blockIdx.y;
    const int n = counts[e];
    const int base = blockIdx.z * TM;
    if (base >= n) return;
    const int m = min(TM, n - base);

    __shared__ ushort_t Xs[TM * XS_LD];   // 16.5 KB
    __shared__ ushort_t Hs[TM * XS_LD];   // 16.5 KB (256 cols used)
    __shared__ int   toks[TM];
    __shared__ float wt_s[TM];

    const int tid = threadIdx.x;
    if (tid < TM) {
        const int* lst = lists + e * T_TOKENS + base;
        const float* wr = wts + e * T_TOKENS + base;
        toks[tid] = (tid < m) ? lst[tid] : -1;
        wt_s[tid] = (tid < m) ? wr[tid] : 0.f;
    }
    __syncthreads();

    // gather X tile: fp32 -> bf16 inline, coalesced 1KB-row reads
    for (int c = tid; c < TM * 32; c += 256) {
        int r = c >> 5, c8 = c & 31;
        int tk = toks[r];
        ushort_t o[8];
        if (tk >= 0) {
            const float* src = x + tk * D_MODEL + c8 * 8;
            float4 v0 = *(const float4*)src;
            float4 v1 = *(const float4*)(src + 4);
            o[0] = f2bf(v0.x); o[1] = f2bf(v0.y); o[2] = f2bf(v0.z); o[3] = f2bf(v0.w);
            o[4] = f2bf(v1.x); o[5] = f2bf(v1.y); o[6] = f2bf(v1.z); o[7] = f2bf(v1.w);
        } else {
#pragma unroll
            for (int j = 0; j < 8; ++j) o[j] = 0;
        }
        *(int4*)(Xs + r * XS_LD + c8 * 8) = *(int4*)o;
    }
    __syncthreads();

    const int lane = tid & 63;
    const int w = tid >> 6;        // wave id: 64-col quarter of the 256 half
    const int l15 = lane & 15;
    const int quad = lane >> 4;

    // ---------------- stage 1: H_half = relu(X @ W1[:,half] + b1) ----------
    const ushort_t* W1p = W1f + (size_t)(e * 32 + half * 16 + w * 4) * 4096 + lane * 8;
    float b1v[4];
#pragma unroll
    for (int nt = 0; nt < 4; ++nt)
        b1v[nt] = b1[e * EXPERT_DIM + half * 256 + w * 64 + nt * 16 + l15];

    f32x4 acc1[2][4] = {};
    short8_t bc[4];
#pragma unroll
    for (int nt = 0; nt < 4; ++nt) bc[nt] = *(const short8_t*)(W1p + nt * 4096);

    for (int ks = 0; ks < 8; ++ks) {
        short8_t bn[4];
        if (ks < 7) {
#pragma unroll
            for (int nt = 0; nt < 4; ++nt)
                bn[nt] = *(const short8_t*)(W1p + nt * 4096 + (ks + 1) * 512);
        }
        short8_t a0 = *(const short8_t*)(Xs + l15 * XS_LD + ks * 32 + quad * 8);
        short8_t a1 = *(const short8_t*)(Xs + (16 + l15) * XS_LD + ks * 32 + quad * 8);
#pragma unroll
        for (int nt = 0; nt < 4; ++nt) {
            acc1[0][nt] = __builtin_amdgcn_mfma_f32_16x16x32_bf16(a0, bc[nt], acc1[0][nt], 0, 0, 0);
            acc1[1][nt] = __builtin_amdgcn_mfma_f32_16x16x32_bf16(a1, bc[nt], acc1[1][nt], 0, 0, 0);
        }
        if (ks < 7) {
#pragma unroll
            for (int nt = 0; nt < 4; ++nt) bc[nt] = bn[nt];
        }
    }
#pragma unroll
    for (int mt = 0; mt < 2; ++mt)
#pragma unroll
        for (int nt = 0; nt < 4; ++nt)
#pragma unroll
            for (int r = 0; r < 4; ++r) {
                int row = mt * 16 + quad * 4 + r;
                int col = w * 64 + nt * 16 + l15;
                float h = fmaxf(acc1[mt][nt][r] + b1v[nt], 0.f);
                Hs[row * XS_LD + col] = f2bf(h);
            }
    __syncthreads();

    // ---------------- stage 2: Y += H_half @ W2[half rows, :] --------------
    const ushort_t* W2p = W2f + (size_t)((e * 2 + half) * 16 + w * 4) * 4096 + lane * 8;
    float b2v[4];
#pragma unroll
    for (int nt = 0; nt < 4; ++nt)
        b2v[nt] = half ? b2[e * D_MODEL + w * 64 + nt * 16 + l15] : 0.f;

    f32x4 acc2[2][4] = {};
    short8_t bc2[4];
#pragma unroll
    for (int nt = 0; nt < 4; ++nt) bc2[nt] = *(const short8_t*)(W2p + nt * 4096);

    for (int ks = 0; ks < 8; ++ks) {
        short8_t bn2[4];
        if (ks < 7) {
#pragma unroll
            for (int nt = 0; nt < 4; ++nt)
                bn2[nt] = *(const short8_t*)(W2p + nt * 4096 + (ks + 1) * 512);
        }
        short8_t a0 = *(const short8_t*)(Hs + l15 * XS_LD + ks * 32 + quad * 8);
        short8_t a1 = *(const short8_t*)(Hs + (16 + l15) * XS_LD + ks * 32 + quad * 8);
#pragma unroll
        for (int nt = 0; nt < 4; ++nt) {
            acc2[0][nt] = __builtin_amdgcn_mfma_f32_16x16x32_bf16(a0, bc2[nt], acc2[0][nt], 0, 0, 0);
            acc2[1][nt] = __builtin_amdgcn_mfma_f32_16x16x32_bf16(a1, bc2[nt], acc2[1][nt], 0, 0, 0);
        }
        if (ks < 7) {
#pragma unroll
            for (int nt = 0; nt < 4; ++nt) bc2[nt] = bn2[nt];
        }
    }

    // epilogue
#pragma unroll
    for (int mt = 0; mt < 2; ++mt)
#pragma unroll
        for (int nt = 0; nt < 4; ++nt)
#pragma unroll
            for (int r = 0; r < 4; ++r) {
                int row = mt * 16 + quad * 4 + r;
                int tk = toks[row];
                if (tk >= 0) {
                    int col = w * 64 + nt * 16 + l15;
                    atomicAdd(&out[tk * D_MODEL + col],
                              wt_s[row] * (acc2[mt][nt][r] + b2v[nt]));
                }
            }
}

extern "C" void kernel_launch(void* const* d_in, const int* in_sizes, int n_in,
                              void* d_out, int out_size, void* d_ws, size_t ws_size,
                              hipStream_t stream)
{
    const float* x    = (const float*)d_in[0];
    const float* Wg   = (const float*)d_in[1];
    const float* bg   = (const float*)d_in[2];
    const float* bias = (const float*)d_in[3];
    const float* W1   = (const float*)d_in[4];
    const float* b1   = (const float*)d_in[5];
    const float* W2   = (const float*)d_in[6];
    const float* b2   = (const float*)d_in[7];
    float* out = (float*)d_out;

    // workspace layout
    char* ws = (char*)d_ws;
    int*      counts = (int*)ws;                                   // 256 B
    int*      lists  = (int*)(ws + 256);                           // 128 KB
    float*    wts    = (float*)(ws + 256 + 131072);                // 128 KB
    ushort_t* W1f    = (ushort_t*)(ws + 256 + 262144);             // 2 MB
    ushort_t* W2f    = (ushort_t*)(ws + 256 + 262144 + 2097152);   // 2 MB

    hipMemsetAsync(out, 0, (size_t)out_size * sizeof(float), stream);
    hipMemsetAsync(counts, 0, NUM_EXPERTS * sizeof(int), stream);

    convert_frag_kernel<<<1024, 256, 0, stream>>>(W1, W2, W1f, W2f);

    moe_gate_kernel<<<T_TOKENS / 256, 256, 0, stream>>>(
        x, Wg, bg, bias, counts, lists, wts);

    moe_expert_mfma<<<dim3(NUM_EXPERTS, 2, T_TOKENS / TM), 256, 0, stream>>>(
        x, W1f, b1, W2f, b2, counts, lists, wts, out);
}